// Round 1
// baseline (9798.540 us; speedup 1.0000x reference)
//
#include <hip/hip_runtime.h>
#include <hip/hip_bf16.h>
#include <stdint.h>

#define HDIM 2048
#define BATCH 16
#define TLEN 512
#define MTOT 8192           // BATCH*TLEN
#define TH   1048576        // TLEN*HDIM
#define OUT_MAIN 16777216   // BATCH*TLEN*HDIM

using floatx4 = __attribute__((ext_vector_type(4))) float;
using shortx8 = __attribute__((ext_vector_type(8))) short;

// ---------------- cast kernels ----------------
__global__ void cast_x_kernel(const float* __restrict__ x, __hip_bfloat16* __restrict__ xb, int n) {
    int i = blockIdx.x * blockDim.x + threadIdx.x;
    int stride = gridDim.x * blockDim.x;
    for (; i < n; i += stride) xb[i] = __float2bfloat16(x[i]);
}

__global__ void cast_w_kernel(const float* __restrict__ W,
                              __hip_bfloat16* __restrict__ wxb,
                              __hip_bfloat16* __restrict__ whb) {
    int i = blockIdx.x * blockDim.x + threadIdx.x;
    int stride = gridDim.x * blockDim.x;
    for (; i < HDIM * HDIM; i += stride) {
        int g = i >> 11, k = i & (HDIM - 1);
        wxb[i] = __float2bfloat16(W[g * (2 * HDIM) + k]);
        whb[i] = __float2bfloat16(W[g * (2 * HDIM) + HDIM + k]);
    }
}

// ---------------- phase A: u = x @ Wx^T + b  -> d_out ----------------
// 128x128 tile, BK=32, 256 threads (4 waves), 16x16x32 bf16 MFMA.
// LDS layout per tile: chunk index = kg*128 + row  (kg = k/8 within BK, 16B chunks)
__global__ __launch_bounds__(256) void gemm_u_kernel(
    const __hip_bfloat16* __restrict__ xb,   // [8192][2048]
    const __hip_bfloat16* __restrict__ wxb,  // [2048][2048]
    const float* __restrict__ bias,          // [2048]
    float* __restrict__ out)                 // [8192][2048]
{
    __shared__ __align__(16) __hip_bfloat16 As[4 * 128 * 8];  // 8 KB
    __shared__ __align__(16) __hip_bfloat16 Bs[4 * 128 * 8];  // 8 KB

    const int j = threadIdx.x;
    const int m0 = blockIdx.x * 128;
    const int n0 = blockIdx.y * 128;
    const int w = j >> 6, lane = j & 63;
    const int wm = (w >> 1) * 64, wn = (w & 1) * 64;
    const int quad = lane >> 4, l15 = lane & 15;

    // staging: thread j covers linear chunk ids j and j+256 (kg = id>>7, row = id&127)
    const int mA0 = j & 127, kg0 = j >> 7;
    const int mA1 = (j + 256) & 127, kg1 = (j + 256) >> 7;

    floatx4 acc[4][4] = {};

    // prefetch k-tile 0
    shortx8 ra0 = *(const shortx8*)(xb  + (size_t)(m0 + mA0) * HDIM + kg0 * 8);
    shortx8 ra1 = *(const shortx8*)(xb  + (size_t)(m0 + mA1) * HDIM + kg1 * 8);
    shortx8 rb0 = *(const shortx8*)(wxb + (size_t)(n0 + mA0) * HDIM + kg0 * 8);
    shortx8 rb1 = *(const shortx8*)(wxb + (size_t)(n0 + mA1) * HDIM + kg1 * 8);

    for (int kt = 0; kt < 64; ++kt) {
        ((shortx8*)As)[kg0 * 128 + mA0] = ra0;
        ((shortx8*)As)[kg1 * 128 + mA1] = ra1;
        ((shortx8*)Bs)[kg0 * 128 + mA0] = rb0;
        ((shortx8*)Bs)[kg1 * 128 + mA1] = rb1;
        __syncthreads();

        if (kt < 63) {
            int k = (kt + 1) * 32;
            ra0 = *(const shortx8*)(xb  + (size_t)(m0 + mA0) * HDIM + k + kg0 * 8);
            ra1 = *(const shortx8*)(xb  + (size_t)(m0 + mA1) * HDIM + k + kg1 * 8);
            rb0 = *(const shortx8*)(wxb + (size_t)(n0 + mA0) * HDIM + k + kg0 * 8);
            rb1 = *(const shortx8*)(wxb + (size_t)(n0 + mA1) * HDIM + k + kg1 * 8);
        }

        shortx8 af[4], bf[4];
#pragma unroll
        for (int mt = 0; mt < 4; ++mt)
            af[mt] = ((const shortx8*)As)[quad * 128 + wm + mt * 16 + l15];
#pragma unroll
        for (int nt = 0; nt < 4; ++nt)
            bf[nt] = ((const shortx8*)Bs)[quad * 128 + wn + nt * 16 + l15];
#pragma unroll
        for (int mt = 0; mt < 4; ++mt)
#pragma unroll
            for (int nt = 0; nt < 4; ++nt)
                acc[mt][nt] = __builtin_amdgcn_mfma_f32_16x16x32_bf16(af[mt], bf[nt], acc[mt][nt], 0, 0, 0);
        __syncthreads();
    }

    // epilogue: C/D layout col=lane&15, row=quad*4+r  (m89-verified)
#pragma unroll
    for (int nt = 0; nt < 4; ++nt) {
        int gn = n0 + wn + nt * 16 + l15;
        float bv = bias[gn];
#pragma unroll
        for (int mt = 0; mt < 4; ++mt) {
#pragma unroll
            for (int r = 0; r < 4; ++r) {
                int gm = m0 + wm + mt * 16 + quad * 4 + r;
                out[(size_t)gm * HDIM + gn] = acc[mt][nt][r] + bv;
            }
        }
    }
}

// ---------------- phase B: persistent recurrence ----------------
// 64 WGs x 512 threads. WG i owns output rows n in [i*32, i*32+32), all 16 batches.
// Wh A-frags register-resident. h double-buffered in ws, layout: elem[kg*128 + b*8 + j]
// = h[b][kg*8+j] (bf16), so staging is a flat 64KB copy and B-frag reads are b128,
// conflict-free. Barrier: monotonic agent-scope atomic counter.
__global__ __launch_bounds__(512) void rnn_scan_kernel(
    const __hip_bfloat16* __restrict__ whb,  // [2048][2048] Wh[g][k]
    __hip_bfloat16* __restrict__ hbuf,       // [2][32768]
    float* __restrict__ out,                 // d_out (u in place -> h in place, + tail h_last)
    unsigned* __restrict__ cnt)
{
    __shared__ __align__(16) unsigned char smem[65536];
    __hip_bfloat16* hs = (__hip_bfloat16*)smem;  // 64 KB during staging/frag reads
    float* ps = (float*)smem;                    // partial[8 waves][2 gt][16 row][17] (aliased, after sync)

    const int j = threadIdx.x;
    const int w = j >> 6, lane = j & 63;
    const int quad = lane >> 4, l15 = lane & 15;
    const int n0 = blockIdx.x * 32;

    // preload Wh A-frags: wave w owns k in [w*256, w*256+256) as 8 chunks of 32
    shortx8 af[2][8];
#pragma unroll
    for (int gt = 0; gt < 2; ++gt)
#pragma unroll
        for (int c = 0; c < 8; ++c) {
            int row = n0 + gt * 16 + l15;
            int k = w * 256 + c * 32 + quad * 8;
            af[gt][c] = *(const shortx8*)(whb + (size_t)row * HDIM + k);
        }

    // reduce-phase mapping: one (n_local, b) pair per thread
    const int rn = j & 31, rb = j >> 5;
    const int gt_r = rn >> 4, row_r = rn & 15;

    for (int t = 0; t < TLEN; ++t) {
        const __hip_bfloat16* hprev = hbuf + (size_t)(t & 1) * 32768;
        __hip_bfloat16* hnext = hbuf + (size_t)((t + 1) & 1) * 32768;

        // prefetch this thread's u value (written by gemm_u; only this WG touches it)
        float uv = out[(size_t)rb * TH + (size_t)t * HDIM + n0 + rn];

        // stage h_{t-1} -> LDS (flat 64KB copy, coalesced, conflict-free)
        shortx8 st[8];
#pragma unroll
        for (int i = 0; i < 8; ++i) st[i] = *(const shortx8*)(hprev + (i * 512 + j) * 8);
#pragma unroll
        for (int i = 0; i < 8; ++i) ((shortx8*)hs)[i * 512 + j] = st[i];
        __syncthreads();

        // MFMA: out tile M=n(2x16), N=b(16), each wave a K-slice of 256
        floatx4 acc[2] = {};
#pragma unroll
        for (int c = 0; c < 8; ++c) {
            int kg = w * 32 + c * 4 + quad;
            shortx8 bfrag = ((const shortx8*)hs)[kg * 16 + l15];
            acc[0] = __builtin_amdgcn_mfma_f32_16x16x32_bf16(af[0][c], bfrag, acc[0], 0, 0, 0);
            acc[1] = __builtin_amdgcn_mfma_f32_16x16x32_bf16(af[1][c], bfrag, acc[1], 0, 0, 0);
        }
        __syncthreads();  // everyone done reading hs before aliasing it with partials

        // write K-partials to LDS (row = quad*4+r, col = b)
#pragma unroll
        for (int gt = 0; gt < 2; ++gt)
#pragma unroll
            for (int r = 0; r < 4; ++r)
                ps[((w * 2 + gt) * 16 + quad * 4 + r) * 17 + l15] = acc[gt][r];
        __syncthreads();

        // reduce across 8 waves, add u, write h
        float s = uv;
#pragma unroll
        for (int ww = 0; ww < 8; ++ww)
            s += ps[((ww * 2 + gt_r) * 16 + row_r) * 17 + rb];

        int n = n0 + rn;
        out[(size_t)rb * TH + (size_t)t * HDIM + n] = s;
        hnext[(n >> 3) * 128 + rb * 8 + (n & 7)] = __float2bfloat16(s);
        if (t == TLEN - 1) out[(size_t)OUT_MAIN + (size_t)rb * HDIM + n] = s;

        // device barrier (monotonic counter; reads precede arrival -> dbuf race-free)
        __threadfence();
        __syncthreads();
        if (j == 0) {
            __hip_atomic_fetch_add(cnt, 1u, __ATOMIC_RELEASE, __HIP_MEMORY_SCOPE_AGENT);
            unsigned target = 64u * (unsigned)(t + 1);
            while (__hip_atomic_load(cnt, __ATOMIC_ACQUIRE, __HIP_MEMORY_SCOPE_AGENT) < target) {
                __builtin_amdgcn_s_sleep(1);
            }
        }
        __syncthreads();
        __builtin_amdgcn_fence(__ATOMIC_ACQUIRE, "agent");
    }
}

// ---------------- launcher ----------------
extern "C" void kernel_launch(void* const* d_in, const int* in_sizes, int n_in,
                              void* d_out, int out_size, void* d_ws, size_t ws_size,
                              hipStream_t stream) {
    (void)in_sizes; (void)n_in; (void)out_size; (void)ws_size;
    const float* x    = (const float*)d_in[0];
    const float* W    = (const float*)d_in[1];
    const float* bias = (const float*)d_in[2];
    float* out = (float*)d_out;
    char* ws = (char*)d_ws;

    __hip_bfloat16* xb   = (__hip_bfloat16*)(ws);                      // 33,554,432 B
    __hip_bfloat16* wxb  = (__hip_bfloat16*)(ws + 33554432);           //  8,388,608 B
    __hip_bfloat16* whb  = (__hip_bfloat16*)(ws + 41943040);           //  8,388,608 B
    __hip_bfloat16* hbuf = (__hip_bfloat16*)(ws + 50331648);           //    131,072 B
    unsigned* cnt        = (unsigned*)(ws + 50331648 + 131072);        //        128 B

    // zero h0 buffer + barrier counter (ws is re-poisoned before every launch)
    hipMemsetAsync(ws + 50331648, 0, 131072 + 128, stream);

    cast_x_kernel<<<8192, 256, 0, stream>>>(x, xb, OUT_MAIN);
    cast_w_kernel<<<8192, 256, 0, stream>>>(W, wxb, whb);
    gemm_u_kernel<<<dim3(64, 16), 256, 0, stream>>>(xb, wxb, bias, out);
    rnn_scan_kernel<<<64, 512, 0, stream>>>(whb, hbuf, out, cnt);
}

// Round 2
// 1766.655 us; speedup vs baseline: 5.5464x; 5.5464x over previous
//
#include <hip/hip_runtime.h>
#include <hip/hip_bf16.h>
#include <stdint.h>

#define HDIM 2048
#define BATCH 16
#define TLEN 512
#define MTOT 8192           // BATCH*TLEN
#define TH   1048576        // TLEN*HDIM
#define OUT_MAIN 16777216   // BATCH*TLEN*HDIM

using floatx4 = __attribute__((ext_vector_type(4))) float;
using shortx8 = __attribute__((ext_vector_type(8))) short;
typedef unsigned long long ull;

// ---------------- cast kernels ----------------
__global__ void cast_x_kernel(const float* __restrict__ x, __hip_bfloat16* __restrict__ xb, int n) {
    int i = blockIdx.x * blockDim.x + threadIdx.x;
    int stride = gridDim.x * blockDim.x;
    for (; i < n; i += stride) xb[i] = __float2bfloat16(x[i]);
}

__global__ void cast_w_kernel(const float* __restrict__ W,
                              __hip_bfloat16* __restrict__ wxb,
                              __hip_bfloat16* __restrict__ whb) {
    int i = blockIdx.x * blockDim.x + threadIdx.x;
    int stride = gridDim.x * blockDim.x;
    for (; i < HDIM * HDIM; i += stride) {
        int g = i >> 11, k = i & (HDIM - 1);
        wxb[i] = __float2bfloat16(W[g * (2 * HDIM) + k]);
        whb[i] = __float2bfloat16(W[g * (2 * HDIM) + HDIM + k]);
    }
}

// ---------------- phase A: u = x @ Wx^T + b  -> d_out ----------------
__global__ __launch_bounds__(256) void gemm_u_kernel(
    const __hip_bfloat16* __restrict__ xb,   // [8192][2048]
    const __hip_bfloat16* __restrict__ wxb,  // [2048][2048]
    const float* __restrict__ bias,          // [2048]
    float* __restrict__ out)                 // [8192][2048]
{
    __shared__ __align__(16) __hip_bfloat16 As[4 * 128 * 8];  // 8 KB
    __shared__ __align__(16) __hip_bfloat16 Bs[4 * 128 * 8];  // 8 KB

    const int j = threadIdx.x;
    const int m0 = blockIdx.x * 128;
    const int n0 = blockIdx.y * 128;
    const int w = j >> 6, lane = j & 63;
    const int wm = (w >> 1) * 64, wn = (w & 1) * 64;
    const int quad = lane >> 4, l15 = lane & 15;

    const int mA0 = j & 127, kg0 = j >> 7;
    const int mA1 = (j + 256) & 127, kg1 = (j + 256) >> 7;

    floatx4 acc[4][4] = {};

    shortx8 ra0 = *(const shortx8*)(xb  + (size_t)(m0 + mA0) * HDIM + kg0 * 8);
    shortx8 ra1 = *(const shortx8*)(xb  + (size_t)(m0 + mA1) * HDIM + kg1 * 8);
    shortx8 rb0 = *(const shortx8*)(wxb + (size_t)(n0 + mA0) * HDIM + kg0 * 8);
    shortx8 rb1 = *(const shortx8*)(wxb + (size_t)(n0 + mA1) * HDIM + kg1 * 8);

    for (int kt = 0; kt < 64; ++kt) {
        ((shortx8*)As)[kg0 * 128 + mA0] = ra0;
        ((shortx8*)As)[kg1 * 128 + mA1] = ra1;
        ((shortx8*)Bs)[kg0 * 128 + mA0] = rb0;
        ((shortx8*)Bs)[kg1 * 128 + mA1] = rb1;
        __syncthreads();

        if (kt < 63) {
            int k = (kt + 1) * 32;
            ra0 = *(const shortx8*)(xb  + (size_t)(m0 + mA0) * HDIM + k + kg0 * 8);
            ra1 = *(const shortx8*)(xb  + (size_t)(m0 + mA1) * HDIM + k + kg1 * 8);
            rb0 = *(const shortx8*)(wxb + (size_t)(n0 + mA0) * HDIM + k + kg0 * 8);
            rb1 = *(const shortx8*)(wxb + (size_t)(n0 + mA1) * HDIM + k + kg1 * 8);
        }

        shortx8 af[4], bf[4];
#pragma unroll
        for (int mt = 0; mt < 4; ++mt)
            af[mt] = ((const shortx8*)As)[quad * 128 + wm + mt * 16 + l15];
#pragma unroll
        for (int nt = 0; nt < 4; ++nt)
            bf[nt] = ((const shortx8*)Bs)[quad * 128 + wn + nt * 16 + l15];
#pragma unroll
        for (int mt = 0; mt < 4; ++mt)
#pragma unroll
            for (int nt = 0; nt < 4; ++nt)
                acc[mt][nt] = __builtin_amdgcn_mfma_f32_16x16x32_bf16(af[mt], bf[nt], acc[mt][nt], 0, 0, 0);
        __syncthreads();
    }

#pragma unroll
    for (int nt = 0; nt < 4; ++nt) {
        int gn = n0 + wn + nt * 16 + l15;
        float bv = bias[gn];
#pragma unroll
        for (int mt = 0; mt < 4; ++mt) {
#pragma unroll
            for (int r = 0; r < 4; ++r) {
                int gm = m0 + wm + mt * 16 + quad * 4 + r;
                out[(size_t)gm * HDIM + gn] = acc[mt][nt][r] + bv;
            }
        }
    }
}

// ---------------- phase B: persistent recurrence ----------------
// 64 WGs x 512 threads. WG i owns output rows n in [i*32, i*32+32), all 16 batches.
// Cross-WG data (hbuf, flags) accessed ONLY via relaxed agent-scope atomics ->
// sc0/sc1 set, bypass L1/L2, complete at the coherent LLC. NO agent fences in
// the loop (agent acquire/release emit buffer_inv / buffer_wbl2 = full-L2
// invalidate/writeback each step -- that was the 18.6us/step in round 1).
// Barrier: per-WG flag words 128B apart; leader stores t+1; wave 0's 64 lanes
// poll one flag each. __syncthreads() drains vmcnt(0) before s_barrier, so
// h-stores are LLC-visible before the flag store.
__global__ __launch_bounds__(512) void rnn_scan_kernel(
    const __hip_bfloat16* __restrict__ whb,  // [2048][2048] Wh[g][k]
    __hip_bfloat16* __restrict__ hbuf,       // [2][32768], layout elem[(k>>3)*128 + b*8 + (k&7)]
    float* __restrict__ out,                 // d_out (u in place -> h in place, + tail h_last)
    unsigned* __restrict__ flags)            // [64][32] uint, 128B stride
{
    __shared__ __align__(16) unsigned char smem[65536];
    __hip_bfloat16* hs = (__hip_bfloat16*)smem;  // 64 KB staging
    float* ps = (float*)smem;                    // aliased partials after sync

    const int j = threadIdx.x;
    const int w = j >> 6, lane = j & 63;
    const int quad = lane >> 4, l15 = lane & 15;
    const int n0 = blockIdx.x * 32;

    // preload Wh A-frags: wave w owns k in [w*256, w*256+256)
    shortx8 af[2][8];
#pragma unroll
    for (int gt = 0; gt < 2; ++gt)
#pragma unroll
        for (int c = 0; c < 8; ++c) {
            int row = n0 + gt * 16 + l15;
            int k = w * 256 + c * 32 + quad * 8;
            af[gt][c] = *(const shortx8*)(whb + (size_t)row * HDIM + k);
        }

    // reduce-phase mapping: one (n_local, b) pair per thread
    const int rn = j & 31, rb = j >> 5;
    const int gt_r = rn >> 4, row_r = rn & 15;

    for (int t = 0; t < TLEN; ++t) {
        const ull* hprev = (const ull*)(hbuf + (size_t)(t & 1) * 32768);
        __hip_bfloat16* hnext = hbuf + (size_t)((t + 1) & 1) * 32768;

        float uv = out[(size_t)rb * TH + (size_t)t * HDIM + n0 + rn];

        // stage h_{t-1} -> LDS: 8192 qwords via relaxed agent loads (LLC-direct)
        ull st[16];
#pragma unroll
        for (int i = 0; i < 16; ++i)
            st[i] = __hip_atomic_load(hprev + i * 512 + j, __ATOMIC_RELAXED, __HIP_MEMORY_SCOPE_AGENT);
#pragma unroll
        for (int i = 0; i < 16; ++i) ((ull*)hs)[i * 512 + j] = st[i];
        __syncthreads();

        // MFMA: out tile M=n(2x16), N=b(16), each wave a K-slice of 256
        floatx4 acc[2] = {};
#pragma unroll
        for (int c = 0; c < 8; ++c) {
            int kg = w * 32 + c * 4 + quad;
            shortx8 bfrag = ((const shortx8*)hs)[kg * 16 + l15];
            acc[0] = __builtin_amdgcn_mfma_f32_16x16x32_bf16(af[0][c], bfrag, acc[0], 0, 0, 0);
            acc[1] = __builtin_amdgcn_mfma_f32_16x16x32_bf16(af[1][c], bfrag, acc[1], 0, 0, 0);
        }
        __syncthreads();  // done reading hs before aliasing with partials

        // write K-partials to LDS (row = quad*4+r, col = b)
#pragma unroll
        for (int gt = 0; gt < 2; ++gt)
#pragma unroll
            for (int r = 0; r < 4; ++r)
                ps[((w * 2 + gt) * 16 + quad * 4 + r) * 17 + l15] = acc[gt][r];
        __syncthreads();

        // reduce across 8 waves, add u
        float s = uv;
#pragma unroll
        for (int ww = 0; ww < 8; ++ww)
            s += ps[((ww * 2 + gt_r) * 16 + row_r) * 17 + rb];

        int n = n0 + rn;
        out[(size_t)rb * TH + (size_t)t * HDIM + n] = s;
        if (t == TLEN - 1) out[(size_t)OUT_MAIN + (size_t)rb * HDIM + n] = s;

        // pack 4 adjacent-n bf16 into one 8B relaxed agent store (lanes j%4==0)
        __hip_bfloat16 hb = __float2bfloat16(s);
        unsigned sv = (unsigned)*(unsigned short*)&hb;
        unsigned o1 = __shfl_down(sv, 1);
        unsigned o2 = __shfl_down(sv, 2);
        unsigned o3 = __shfl_down(sv, 3);
        if ((j & 3) == 0) {
            ull pack = (ull)(sv | (o1 << 16)) | (((ull)(o2 | (o3 << 16))) << 32);
            int idx = ((n >> 3) * 128 + rb * 8 + (n & 7));  // n%4==0 -> 8B aligned
            __hip_atomic_store((ull*)(hnext + idx), pack, __ATOMIC_RELAXED, __HIP_MEMORY_SCOPE_AGENT);
        }

        // barrier: syncthreads drains vmcnt(0) (h-stores at LLC), then flag store
        __syncthreads();
        if (j == 0)
            __hip_atomic_store(flags + blockIdx.x * 32, (unsigned)(t + 1),
                               __ATOMIC_RELAXED, __HIP_MEMORY_SCOPE_AGENT);
        if (w == 0) {
            const unsigned* fp = flags + lane * 32;
            unsigned target = (unsigned)(t + 1);
            while (__hip_atomic_load(fp, __ATOMIC_RELAXED, __HIP_MEMORY_SCOPE_AGENT) < target)
                __builtin_amdgcn_s_sleep(2);
        }
        __syncthreads();
    }
}

// ---------------- launcher ----------------
extern "C" void kernel_launch(void* const* d_in, const int* in_sizes, int n_in,
                              void* d_out, int out_size, void* d_ws, size_t ws_size,
                              hipStream_t stream) {
    (void)in_sizes; (void)n_in; (void)out_size; (void)ws_size;
    const float* x    = (const float*)d_in[0];
    const float* W    = (const float*)d_in[1];
    const float* bias = (const float*)d_in[2];
    float* out = (float*)d_out;
    char* ws = (char*)d_ws;

    __hip_bfloat16* xb   = (__hip_bfloat16*)(ws);                      // 33,554,432 B
    __hip_bfloat16* wxb  = (__hip_bfloat16*)(ws + 33554432);           //  8,388,608 B
    __hip_bfloat16* whb  = (__hip_bfloat16*)(ws + 41943040);           //  8,388,608 B
    __hip_bfloat16* hbuf = (__hip_bfloat16*)(ws + 50331648);           //    131,072 B
    unsigned* flags      = (unsigned*)(ws + 50331648 + 131072);        //      8,192 B

    // zero h0 buffer + flags (ws is re-poisoned before every launch)
    hipMemsetAsync(ws + 50331648, 0, 131072 + 8192, stream);

    cast_x_kernel<<<8192, 256, 0, stream>>>(x, xb, OUT_MAIN);
    cast_w_kernel<<<8192, 256, 0, stream>>>(W, wxb, whb);
    gemm_u_kernel<<<dim3(64, 16), 256, 0, stream>>>(xb, wxb, bias, out);
    rnn_scan_kernel<<<64, 512, 0, stream>>>(whb, hbuf, out, flags);
}

// Round 3
// 1498.141 us; speedup vs baseline: 6.5405x; 1.1792x over previous
//
#include <hip/hip_runtime.h>
#include <hip/hip_bf16.h>
#include <stdint.h>

#define HDIM 2048
#define BATCH 16
#define TLEN 512
#define TH   1048576        // TLEN*HDIM
#define OUT_MAIN 16777216   // BATCH*TLEN*HDIM

using floatx4 = __attribute__((ext_vector_type(4))) float;
using shortx8 = __attribute__((ext_vector_type(8))) short;
typedef unsigned long long ull;

// ---------------- cast kernels ----------------
__global__ void cast_x_kernel(const float* __restrict__ x, __hip_bfloat16* __restrict__ xb, int n) {
    int i = blockIdx.x * blockDim.x + threadIdx.x;
    int stride = gridDim.x * blockDim.x;
    for (; i < n; i += stride) xb[i] = __float2bfloat16(x[i]);
}

__global__ void cast_w_kernel(const float* __restrict__ W,
                              __hip_bfloat16* __restrict__ wxb,
                              __hip_bfloat16* __restrict__ whb) {
    int i = blockIdx.x * blockDim.x + threadIdx.x;
    int stride = gridDim.x * blockDim.x;
    for (; i < HDIM * HDIM; i += stride) {
        int g = i >> 11, k = i & (HDIM - 1);
        wxb[i] = __float2bfloat16(W[g * (2 * HDIM) + k]);
        whb[i] = __float2bfloat16(W[g * (2 * HDIM) + HDIM + k]);
    }
}

// ---------------- phase A: u = x @ Wx^T + b  -> d_out ----------------
__global__ __launch_bounds__(256) void gemm_u_kernel(
    const __hip_bfloat16* __restrict__ xb,   // [8192][2048]
    const __hip_bfloat16* __restrict__ wxb,  // [2048][2048]
    const float* __restrict__ bias,          // [2048]
    float* __restrict__ out)                 // [8192][2048]
{
    __shared__ __align__(16) __hip_bfloat16 As[4 * 128 * 8];  // 8 KB
    __shared__ __align__(16) __hip_bfloat16 Bs[4 * 128 * 8];  // 8 KB

    const int j = threadIdx.x;
    const int m0 = blockIdx.x * 128;
    const int n0 = blockIdx.y * 128;
    const int w = j >> 6, lane = j & 63;
    const int wm = (w >> 1) * 64, wn = (w & 1) * 64;
    const int quad = lane >> 4, l15 = lane & 15;

    const int mA0 = j & 127, kg0 = j >> 7;
    const int mA1 = (j + 256) & 127, kg1 = (j + 256) >> 7;

    floatx4 acc[4][4] = {};

    shortx8 ra0 = *(const shortx8*)(xb  + (size_t)(m0 + mA0) * HDIM + kg0 * 8);
    shortx8 ra1 = *(const shortx8*)(xb  + (size_t)(m0 + mA1) * HDIM + kg1 * 8);
    shortx8 rb0 = *(const shortx8*)(wxb + (size_t)(n0 + mA0) * HDIM + kg0 * 8);
    shortx8 rb1 = *(const shortx8*)(wxb + (size_t)(n0 + mA1) * HDIM + kg1 * 8);

    for (int kt = 0; kt < 64; ++kt) {
        ((shortx8*)As)[kg0 * 128 + mA0] = ra0;
        ((shortx8*)As)[kg1 * 128 + mA1] = ra1;
        ((shortx8*)Bs)[kg0 * 128 + mA0] = rb0;
        ((shortx8*)Bs)[kg1 * 128 + mA1] = rb1;
        __syncthreads();

        if (kt < 63) {
            int k = (kt + 1) * 32;
            ra0 = *(const shortx8*)(xb  + (size_t)(m0 + mA0) * HDIM + k + kg0 * 8);
            ra1 = *(const shortx8*)(xb  + (size_t)(m0 + mA1) * HDIM + k + kg1 * 8);
            rb0 = *(const shortx8*)(wxb + (size_t)(n0 + mA0) * HDIM + k + kg0 * 8);
            rb1 = *(const shortx8*)(wxb + (size_t)(n0 + mA1) * HDIM + k + kg1 * 8);
        }

        shortx8 af[4], bf[4];
#pragma unroll
        for (int mt = 0; mt < 4; ++mt)
            af[mt] = ((const shortx8*)As)[quad * 128 + wm + mt * 16 + l15];
#pragma unroll
        for (int nt = 0; nt < 4; ++nt)
            bf[nt] = ((const shortx8*)Bs)[quad * 128 + wn + nt * 16 + l15];
#pragma unroll
        for (int mt = 0; mt < 4; ++mt)
#pragma unroll
            for (int nt = 0; nt < 4; ++nt)
                acc[mt][nt] = __builtin_amdgcn_mfma_f32_16x16x32_bf16(af[mt], bf[nt], acc[mt][nt], 0, 0, 0);
        __syncthreads();
    }

#pragma unroll
    for (int nt = 0; nt < 4; ++nt) {
        int gn = n0 + wn + nt * 16 + l15;
        float bv = bias[gn];
#pragma unroll
        for (int mt = 0; mt < 4; ++mt) {
#pragma unroll
            for (int r = 0; r < 4; ++r) {
                int gm = m0 + wm + mt * 16 + quad * 4 + r;
                out[(size_t)gm * HDIM + gn] = acc[mt][nt][r] + bv;
            }
        }
    }
}

// ---------------- phase B: persistent recurrence ----------------
// 64 WGs x 512 threads. WG i owns rows n in [i*32, i*32+32), all 16 batches.
//
// h lives in a RING BUFFER (slot for h_{t+1} = ring + t*32768; h_0 is a
// separate zeroed slot). Each slot is written once (producers: packed-bf16
// relaxed agent-scope stores -> acked at the coherent LLC, bypassing L2) and
// read once per consumer via PLAIN cached b128 loads. Plain loads are safe
// because ring addresses are never revisited: no L1/L2 line can ever be stale,
// and any fetch is flag-gated (producer stores acked before its flag store).
// B-frags load straight from global into VGPRs -- no LDS staging phase at all.
//
// Per-wave producer polling: wave w consumes k-rows [w*256, w*256+256) =
// producer WGs [8w, 8w+8). Lanes 0-7 poll those 8 flags; the wave starts its
// loads+MFMA as soon as ITS producers are done (no WG-wide convergence until
// the partial-sum exchange).
__global__ __launch_bounds__(512) void rnn_scan_kernel(
    const __hip_bfloat16* __restrict__ whb,  // [2048][2048] Wh[g][k]
    __hip_bfloat16* __restrict__ ring,       // [512][32768] slots for h_1..h_512
    const __hip_bfloat16* __restrict__ h0,   // [32768] zeros (h_0)
    float* __restrict__ out,                 // d_out (u in place -> h in place, + tail h_last)
    unsigned* __restrict__ flags)            // [64][32] uint, 128B stride
{
    __shared__ float ps[8 * 2 * 16 * 17];    // 34.8 KB partials

    const int j = threadIdx.x;
    const int w = j >> 6, lane = j & 63;
    const int quad = lane >> 4, l15 = lane & 15;
    const int n0 = blockIdx.x * 32;

    // preload Wh A-frags: wave w owns k in [w*256, w*256+256)
    shortx8 af[2][8];
#pragma unroll
    for (int gt = 0; gt < 2; ++gt)
#pragma unroll
        for (int c = 0; c < 8; ++c) {
            int row = n0 + gt * 16 + l15;
            int k = w * 256 + c * 32 + quad * 8;
            af[gt][c] = *(const shortx8*)(whb + (size_t)row * HDIM + k);
        }

    // reduce-phase mapping: one (n_local, b) pair per thread
    const int rn = j & 31, rb = j >> 5;
    const int gt_r = rn >> 4, row_r = rn & 15;

    for (int t = 0; t < TLEN; ++t) {
        const __hip_bfloat16* hprev = (t == 0) ? h0 : (ring + (size_t)(t - 1) * 32768);
        __hip_bfloat16* hnext = ring + (size_t)t * 32768;

        // prefetch u (independent of flags -> overlaps poll latency)
        float uv = out[(size_t)rb * TH + (size_t)t * HDIM + n0 + rn];

        // wave-local wait: lanes 0-7 each poll one of this wave's 8 producers
        if (lane < 8) {
            const unsigned* fp = flags + (w * 8 + lane) * 32;
            while (__hip_atomic_load(fp, __ATOMIC_RELAXED, __HIP_MEMORY_SCOPE_AGENT) < (unsigned)t) {}
        }
        __asm__ __volatile__("" ::: "memory");  // keep the loads below the poll

        // direct B-frag loads: wave-contiguous 1KB segments, plain cached b128
        shortx8 bfr[8];
#pragma unroll
        for (int c = 0; c < 8; ++c) {
            int kg = w * 32 + c * 4 + quad;
            bfr[c] = *(const shortx8*)(hprev + (size_t)kg * 128 + l15 * 8);
        }

        floatx4 acc[2] = {};
#pragma unroll
        for (int c = 0; c < 8; ++c) {
            acc[0] = __builtin_amdgcn_mfma_f32_16x16x32_bf16(af[0][c], bfr[c], acc[0], 0, 0, 0);
            acc[1] = __builtin_amdgcn_mfma_f32_16x16x32_bf16(af[1][c], bfr[c], acc[1], 0, 0, 0);
        }

        // write K-partials to LDS (row = quad*4+r, col = b; +1 pad)
#pragma unroll
        for (int gt = 0; gt < 2; ++gt)
#pragma unroll
            for (int r = 0; r < 4; ++r)
                ps[((w * 2 + gt) * 16 + quad * 4 + r) * 17 + l15] = acc[gt][r];
        __syncthreads();

        // reduce across 8 waves, add u
        float s = uv;
#pragma unroll
        for (int ww = 0; ww < 8; ++ww)
            s += ps[((ww * 2 + gt_r) * 16 + row_r) * 17 + rb];

        int n = n0 + rn;
        out[(size_t)rb * TH + (size_t)t * HDIM + n] = s;
        if (t == TLEN - 1) out[(size_t)OUT_MAIN + (size_t)rb * HDIM + n] = s;

        // pack 4 adjacent-n bf16 into one 8B relaxed agent store (lanes j%4==0)
        __hip_bfloat16 hb = __float2bfloat16(s);
        unsigned sv = (unsigned)*(unsigned short*)&hb;
        unsigned o1 = __shfl_down(sv, 1);
        unsigned o2 = __shfl_down(sv, 2);
        unsigned o3 = __shfl_down(sv, 3);
        if ((j & 3) == 0) {
            ull pack = (ull)(sv | (o1 << 16)) | (((ull)(o2 | (o3 << 16))) << 32);
            int idx = ((n >> 3) * 128 + rb * 8 + (n & 7));  // n%4==0 -> 8B aligned
            __hip_atomic_store((ull*)(hnext + idx), pack, __ATOMIC_RELAXED, __HIP_MEMORY_SCOPE_AGENT);
        }

        // barrier separates ps reads (above) from next step's writes, and each
        // wave drains vmcnt(0) before s_barrier -> all h stores acked at LLC
        // before the leader publishes the flag.
        __syncthreads();
        if (j == 0)
            __hip_atomic_store(flags + blockIdx.x * 32, (unsigned)(t + 1),
                               __ATOMIC_RELAXED, __HIP_MEMORY_SCOPE_AGENT);
    }
}

// ---------------- launcher ----------------
extern "C" void kernel_launch(void* const* d_in, const int* in_sizes, int n_in,
                              void* d_out, int out_size, void* d_ws, size_t ws_size,
                              hipStream_t stream) {
    (void)in_sizes; (void)n_in; (void)out_size; (void)ws_size;
    const float* x    = (const float*)d_in[0];
    const float* W    = (const float*)d_in[1];
    const float* bias = (const float*)d_in[2];
    float* out = (float*)d_out;
    char* ws = (char*)d_ws;

    // ring (32 MB) ALIASES xb: xb is dead once gemm_u completes, before the scan.
    __hip_bfloat16* xb   = (__hip_bfloat16*)(ws);                      // 33,554,432 B
    __hip_bfloat16* ring = (__hip_bfloat16*)(ws);                      // 512 x 65,536 B
    __hip_bfloat16* wxb  = (__hip_bfloat16*)(ws + 33554432);           //  8,388,608 B
    __hip_bfloat16* whb  = (__hip_bfloat16*)(ws + 41943040);           //  8,388,608 B
    __hip_bfloat16* h0   = (__hip_bfloat16*)(ws + 50331648);           //     65,536 B
    unsigned* flags      = (unsigned*)(ws + 50331648 + 65536);         //      8,192 B

    // zero h_0 slot + flags (ws is re-poisoned before every launch)
    hipMemsetAsync(ws + 50331648, 0, 65536 + 8192, stream);

    cast_x_kernel<<<8192, 256, 0, stream>>>(x, xb, OUT_MAIN);
    cast_w_kernel<<<8192, 256, 0, stream>>>(W, wxb, whb);
    gemm_u_kernel<<<dim3(64, 16), 256, 0, stream>>>(xb, wxb, bias, out);
    rnn_scan_kernel<<<64, 512, 0, stream>>>(whb, ring, h0, out, flags);
}